// Round 10
// baseline (14041.612 us; speedup 1.0000x reference)
//
#include <hip/hip_runtime.h>

// ============================================================================
// 2-layer LSTM, persistent kernel, MI355X — round 10.
// R9 lesson: removing the read/write-separating barrier caused 5.6x LDS bank
// conflicts (ds_read||ds_write collide) -> revert to R7 wholesale.
// R10 single mechanism: h loads were `nt` (LLC-direct) -> 96 MB/phase of LLC
// reads (h re-read 64x per m-tile per layer input). Now h loads are PLAIN
// (L2-allocating, 16x intra-XCD reuse); coherence restored by
// `buffer_inv sc0 sc1` once per wave at phase top (prior-phase sc01 stores
// are LLC-resident after the grid barrier; inv kills stale clean L1/L2 lines
// from phase t-2 reads). h stores stay sc01. Weights/x unchanged.
// Everything else byte-identical to R7 (8.45 ms, absmax 4.9e-3, 6x correct).
// ============================================================================

typedef unsigned int u32;
typedef unsigned short u16;
typedef __attribute__((ext_vector_type(8))) short bf16x8;
typedef __attribute__((ext_vector_type(4))) float f32x4;

#define MFMA __builtin_amdgcn_mfma_f32_16x16x32_bf16
#define HB (256 * 1024)   // h buffer elems per parity

__device__ __forceinline__ u16 f2bf(float f) {
  u32 u = __float_as_uint(f);
  u += 0x7fffu + ((u >> 16) & 1u);   // RNE (inputs finite)
  return (u16)(u >> 16);
}
__device__ __forceinline__ float sigm(float v) { return 1.f / (1.f + __expf(-v)); }
__device__ __forceinline__ float tanh_(float v) { return 1.f - 2.f / (__expf(2.f * v) + 1.f); }

__device__ __forceinline__ u32 ld_u32_sc01(const u32* p) {
  u32 v;
  asm volatile("global_load_dword %0, %1, off sc0 sc1\n\ts_waitcnt vmcnt(0)"
               : "=v"(v) : "v"(p) : "memory");
  return v;
}
__device__ __forceinline__ void st_u32_sc01(u32* p, u32 v) {
  asm volatile("global_store_dword %0, %1, off sc0 sc1" :: "v"(p), "v"(v) : "memory");
}
__device__ __forceinline__ void st_f32_sc01(float* p, float v) {
  asm volatile("global_store_dword %0, %1, off sc0 sc1" :: "v"(p), "v"(v) : "memory");
}
// invalidate L1+L2 (clean lines only matter; sc01 stores never dirty L2)
__device__ __forceinline__ void cache_inv() {
  asm volatile("buffer_inv sc0 sc1\n\ts_waitcnt vmcnt(0)" ::: "memory");
}

// ---------------- prologue: f32 -> bf16 packed-fragment weights ----------------
// (verbatim from R7)
__global__ void __launch_bounds__(256) wconv(
    const float* __restrict__ Wx0, const float* __restrict__ Wh0,
    const float* __restrict__ Wx1, const float* __restrict__ Wh1,
    u16* __restrict__ W1p, u16* __restrict__ W0p, u16* __restrict__ X0p) {
  const u32 NG1 = 1048576u, NG0 = 524288u, NGX = 32768u;
  u32 g = blockIdx.x * 256u + threadIdx.x;
  const float* src; u16* dst;
  if (g < NG1) {
    u32 lane = g & 63u, f = (g >> 6) & 1u, jj = (g >> 7) & 1u, c = (g >> 8) & 7u;
    u32 kway = (g >> 11) & 3u, s = (g >> 13) & 1u, u0idx = g >> 14;
    u32 i15 = lane & 15u, kq = lane >> 4;
    u32 row = (2u * f + (i15 >> 3)) * 1024u + u0idx * 16u + s * 8u + (i15 & 7u);
    u32 k = (kway + 4u * (2u * c + jj)) * 32u + kq * 8u;
    src = (k < 1024u) ? Wx1 + (size_t)row * 1024 + k
                      : Wh1 + (size_t)row * 1024 + (k - 1024u);
    dst = W1p + (size_t)g * 8;
  } else if (g < NG1 + NG0) {
    u32 h = g - NG1;
    u32 lane = h & 63u, f = (h >> 6) & 1u, jj = (h >> 7) & 1u, c = (h >> 8) & 3u;
    u32 kway = (h >> 10) & 3u, s = (h >> 12) & 1u, u0idx = h >> 13;
    u32 i15 = lane & 15u, kq = lane >> 4;
    u32 row = (2u * f + (i15 >> 3)) * 1024u + u0idx * 16u + s * 8u + (i15 & 7u);
    u32 k = (kway + 4u * (2u * c + jj)) * 32u + kq * 8u;
    src = Wh0 + (size_t)row * 1024 + k;
    dst = W0p + (size_t)h * 8;
  } else if (g < NG1 + NG0 + NGX) {
    u32 h = g - NG1 - NG0;
    u32 lane = h & 63u, f = (h >> 6) & 1u, kway = (h >> 7) & 1u;
    u32 s = (h >> 8) & 1u, u0idx = h >> 9;
    u32 i15 = lane & 15u, kq = lane >> 4;
    u32 row = (2u * f + (i15 >> 3)) * 1024u + u0idx * 16u + s * 8u + (i15 & 7u);
    u32 k = kway * 32u + kq * 8u;
    src = Wx0 + (size_t)row * 64 + k;
    dst = X0p + (size_t)h * 8;
  } else return;
  float4 v0 = *(const float4*)src, v1 = *(const float4*)(src + 4);
  bf16x8 r;
  r[0] = (short)f2bf(v0.x); r[1] = (short)f2bf(v0.y);
  r[2] = (short)f2bf(v0.z); r[3] = (short)f2bf(v0.w);
  r[4] = (short)f2bf(v1.x); r[5] = (short)f2bf(v1.y);
  r[6] = (short)f2bf(v1.z); r[7] = (short)f2bf(v1.w);
  *(bf16x8*)dst = r;
}

// ---- per-chunk weight load: bank literal, per-call opaque offset ----
#define LDW(bank, c) do {                                                      \
  u32 o0_ = bW[0] + (u32)((c) * 2048), o1_ = bW[1] + (u32)((c) * 2048);        \
  asm volatile("" : "+v"(o0_), "+v"(o1_));                                     \
  _Pragma("unroll")                                                            \
  for (int jj_ = 0; jj_ < 2; ++jj_)                                            \
    _Pragma("unroll")                                                          \
    for (int f_ = 0; f_ < 2; ++f_) {                                           \
      W[bank][jj_][0][f_] = *(const bf16x8*)(WP + o0_ + (u32)(jj_*1024+f_*512));\
      W[bank][jj_][1][f_] = *(const bf16x8*)(WP + o1_ + (u32)(jj_*1024+f_*512));\
    }                                                                          \
} while (0)

// ---- per-chunk MFMA: 2 ksteps x 4 m-frags x 4 (s,f) n-frags = 32 MFMA ----
#define CHUNK(bank) do {                                                       \
  _Pragma("unroll")                                                            \
  for (int jj_ = 0; jj_ < 2; ++jj_) {                                          \
    const int kin_ = (kway + (jj_ << 2)) << 5;                                 \
    _Pragma("unroll")                                                          \
    for (int mf_ = 0; mf_ < 4; ++mf_) {                                        \
      bf16x8 a_ = readA(mf_, kin_);                                            \
      _Pragma("unroll")                                                        \
      for (int s_ = 0; s_ < 2; ++s_)                                           \
        _Pragma("unroll")                                                      \
        for (int f_ = 0; f_ < 2; ++f_)                                         \
          acc[mf_][s_][f_] = MFMA(a_, W[bank][jj_][s_][f_],                    \
                                  acc[mf_][s_][f_], 0, 0, 0);                  \
    }                                                                          \
  }                                                                            \
} while (0)

__global__ void __launch_bounds__(256, 2)
lstm_persist(const float* __restrict__ x,
             const float* __restrict__ b0, const float* __restrict__ b1,
             const float* __restrict__ fcW, const float* __restrict__ fcb,
             const u16* __restrict__ W1p, const u16* __restrict__ W0p,
             const u16* __restrict__ X0p,
             u16* __restrict__ h0b, u16* __restrict__ h1b,
             float* __restrict__ h1f, u32* __restrict__ bar,
             float* __restrict__ out)
{
  const int tid = threadIdx.x, blk = blockIdx.x;
  const int lane = tid & 63, w = tid >> 6;
  const int kway = w;                 // wave = k-split lane (0..3)
  const int L = blk >> 8;             // 0: layer0 WG, 1: layer1 WG
  const int sub = blk & 255;
  const int m0 = (sub >> 6) << 6;     // batch tile base
  const int u0idx = sub & 63;
  const int u0 = u0idx << 4;          // hidden-unit base

  __shared__ short Abuf[64 * 256];    // single 32KB A chunk
  __shared__ float gA[64][68];        // k-reduce region A
  __shared__ float gB[64][68];        // k-reduce region B
  __shared__ float cbuf[64][16];      // persistent c state (own layer)

  for (int i = tid; i < 64 * 16; i += 256) ((float*)cbuf)[i] = 0.f;

  const int i15 = lane & 15, kq = lane >> 4;

  // packed-weight base offsets for both s-halves (u32 elem offsets)
  u32 bW[2], bX[2];
#pragma unroll
  for (int s_ = 0; s_ < 2; ++s_) {
    u32 key = (u32)((u0idx << 1) | s_);
    bW[s_] = ((key << 2) | (u32)kway) * (L ? 16384u : 8192u) + (u32)lane * 8u;
    bX[s_] = ((key << 1) | (u32)kway) * 1024u + (u32)lane * 8u;  // kway<2 only
  }
  const u16* WP = L ? W1p : W0p;

  float bias[2][2];
#pragma unroll
  for (int s_ = 0; s_ < 2; ++s_)
#pragma unroll
    for (int f_ = 0; f_ < 2; ++f_) {
      int rowf = ((f_ << 1) + (i15 >> 3)) * 1024 + u0 + s_ * 8 + (i15 & 7);
      bias[s_][f_] = (kway == 0) ? (L ? b1[rowf] : b0[rowf]) : 0.f;
    }

  // staging maps: 2048 bf16x8 slots (64 rows x 32), 8 per thread
  int grow[8], ldsoff[8];
#pragma unroll
  for (int cc = 0; cc < 8; ++cc) {
    int slot = cc * 256 + tid;
    int row = slot >> 5, c = slot & 31;
    grow[cc]   = ((m0 + row) << 10) + (c << 3);
    ldsoff[cc] = (row << 8) + ((c ^ (row & 7)) << 3);
  }

  bf16x8 v[8];
  auto stage_ld = [&](const u16* src, int kbase) {   // PLAIN loads (L2-alloc)
#pragma unroll
    for (int cc = 0; cc < 8; ++cc)
      v[cc] = *(const bf16x8*)(src + grow[cc] + kbase);
  };
  auto stage_st = [&]() {
#pragma unroll
    for (int cc = 0; cc < 8; ++cc)
      *(bf16x8*)&Abuf[ldsoff[cc]] = v[cc];
  };

  auto stage_x = [&](int t) {   // x tile 64x64 f32 -> bf16 into Abuf
    int row = tid >> 2, c4 = tid & 3;
    const float* g = x + ((size_t)(m0 + row) * 512 + t) * 64 + (c4 << 4);
    float4 a0 = *(const float4*)g,       a1 = *(const float4*)(g + 4);
    float4 a2 = *(const float4*)(g + 8), a3 = *(const float4*)(g + 12);
    bf16x8 r0, r1;
    r0[0] = (short)f2bf(a0.x); r0[1] = (short)f2bf(a0.y);
    r0[2] = (short)f2bf(a0.z); r0[3] = (short)f2bf(a0.w);
    r0[4] = (short)f2bf(a1.x); r0[5] = (short)f2bf(a1.y);
    r0[6] = (short)f2bf(a1.z); r0[7] = (short)f2bf(a1.w);
    r1[0] = (short)f2bf(a2.x); r1[1] = (short)f2bf(a2.y);
    r1[2] = (short)f2bf(a2.z); r1[3] = (short)f2bf(a2.w);
    r1[4] = (short)f2bf(a3.x); r1[5] = (short)f2bf(a3.y);
    r1[6] = (short)f2bf(a3.z); r1[7] = (short)f2bf(a3.w);
    int c = c4 << 1;
    *(bf16x8*)&Abuf[(row << 8) + (((c    ) ^ (row & 7)) << 3)] = r0;
    *(bf16x8*)&Abuf[(row << 8) + (((c + 1) ^ (row & 7)) << 3)] = r1;
  };

  auto readA = [&](int mf, int kin) -> bf16x8 {
    int row = (mf << 4) | i15;
    int c = ((kin >> 3) + kq) ^ (row & 7);
    return *(const bf16x8*)&Abuf[(row << 8) + (c << 3)];
  };

  bf16x8 W[2][2][2][2];   // [bank][jj][s][f] double-banked weights (64 regs)
  f32x4 acc[4][2][2];     // [mf][s][f] (64 regs)

  auto acc_init = [&]() {
#pragma unroll
    for (int mf = 0; mf < 4; ++mf)
#pragma unroll
      for (int s_ = 0; s_ < 2; ++s_)
#pragma unroll
        for (int f_ = 0; f_ < 2; ++f_) {
          float bv = bias[s_][f_];
          acc[mf][s_][f_][0] = bv; acc[mf][s_][f_][1] = bv;
          acc[mf][s_][f_][2] = bv; acc[mf][s_][f_][3] = bv;
        }
  };

  auto reduce2 = [&]() {   // 4 kway partials -> gA + gB
    if (kway < 2) {
      float (*g)[68] = kway ? gB : gA;
#pragma unroll
      for (int mf = 0; mf < 4; ++mf)
#pragma unroll
        for (int s_ = 0; s_ < 2; ++s_)
#pragma unroll
          for (int f_ = 0; f_ < 2; ++f_)
#pragma unroll
            for (int r = 0; r < 4; ++r)
              g[(mf << 4) + (kq << 2) + r][(s_ << 5) + (f_ << 4) + i15] = acc[mf][s_][f_][r];
    }
    __syncthreads();
    if (kway >= 2) {
      float (*g)[68] = (kway == 3) ? gB : gA;
#pragma unroll
      for (int mf = 0; mf < 4; ++mf)
#pragma unroll
        for (int s_ = 0; s_ < 2; ++s_)
#pragma unroll
          for (int f_ = 0; f_ < 2; ++f_)
#pragma unroll
            for (int r = 0; r < 4; ++r)
              g[(mf << 4) + (kq << 2) + r][(s_ << 5) + (f_ << 4) + i15] += acc[mf][s_][f_][r];
    }
    __syncthreads();
  };

  auto ew = [&](u16* hdst, bool wf32) {
    int row = tid >> 2, un = (tid & 3) << 2;   // 4 units per thread
    float hq[4];
#pragma unroll
    for (int q = 0; q < 4; ++q) {
      int u = un + q;
      int cb = ((u >> 3) << 5) | (u & 7);
      float gi = gA[row][cb]      + gB[row][cb];
      float gf = gA[row][cb + 8]  + gB[row][cb + 8];
      float gg = gA[row][cb + 16] + gB[row][cb + 16];
      float go = gA[row][cb + 24] + gB[row][cb + 24];
      float ii = sigm(gi), ff = sigm(gf), g2 = tanh_(gg), oo = sigm(go);
      float c = ff * cbuf[row][u] + ii * g2;
      cbuf[row][u] = c;
      hq[q] = oo * tanh_(c);
    }
    size_t idx = ((size_t)(m0 + row) << 10) + u0 + un;
    st_u32_sc01((u32*)(hdst + idx),     (u32)f2bf(hq[0]) | ((u32)f2bf(hq[1]) << 16));
    st_u32_sc01((u32*)(hdst + idx + 2), (u32)f2bf(hq[2]) | ((u32)f2bf(hq[3]) << 16));
    if (wf32) {
      st_f32_sc01(h1f + idx,     hq[0]); st_f32_sc01(h1f + idx + 1, hq[1]);
      st_f32_sc01(h1f + idx + 2, hq[2]); st_f32_sc01(h1f + idx + 3, hq[3]);
    }
  };

  auto gridbar = [&](int t) {       // verbatim R7 leader-tree barrier
    __syncthreads();                // drains vmcnt -> sc01 h stores at LLC
    if (tid == 0) {
      const int g = blk & 7;
      u32* gc   = bar + g * 32;
      u32* root = bar + 256;
      u32* gen  = bar + 288 + g * 32;
      const u32 p1 = (u32)(t + 1);
      __hip_atomic_fetch_add(gc, 1u, __ATOMIC_RELAXED, __HIP_MEMORY_SCOPE_AGENT);
      if (blk < 8) {
        while (ld_u32_sc01(gc) < 64u * p1) __builtin_amdgcn_s_sleep(4);
        __hip_atomic_fetch_add(root, 1u, __ATOMIC_RELAXED, __HIP_MEMORY_SCOPE_AGENT);
        while (ld_u32_sc01(root) < 8u * p1) __builtin_amdgcn_s_sleep(2);
        st_u32_sc01(gen, p1);
      } else {
        while (ld_u32_sc01(gen) < p1) __builtin_amdgcn_s_sleep(4);
      }
    }
    __syncthreads();
  };

  if (L == 0) {
    // ---------------- layer-0 WGs: compute h0(t) each phase ----------------
#pragma unroll 1
    for (int t = 0; t <= 512; ++t) {
      if (t < 512) {
        cache_inv();                       // kill stale h lines from t-2 reads
        const u16* h0rd = h0b + ((t + 1) & 1) * HB;
        u16* h0wr = h0b + (t & 1) * HB;
        acc_init();
        stage_x(t);                        // Abuf <- x tile
        stage_ld(h0rd, 0);                 // prefetch h0 chunk0
        bf16x8 X[2][2];
        if (kway < 2) {
          u32 ox0 = bX[0], ox1 = bX[1];
          asm volatile("" : "+v"(ox0), "+v"(ox1));
          X[0][0] = *(const bf16x8*)(X0p + ox0);
          X[0][1] = *(const bf16x8*)(X0p + ox0 + 512u);
          X[1][0] = *(const bf16x8*)(X0p + ox1);
          X[1][1] = *(const bf16x8*)(X0p + ox1 + 512u);
        }
        LDW(0, 0);                         // W chunk0 -> bank0
        __syncthreads();                   // x tile ready
        if (kway < 2) {                    // x-tick (ksteps 0,1 of K=64)
          const int kin = kway << 5;
#pragma unroll
          for (int mf = 0; mf < 4; ++mf) {
            bf16x8 a = readA(mf, kin);
#pragma unroll
            for (int s_ = 0; s_ < 2; ++s_)
#pragma unroll
              for (int f_ = 0; f_ < 2; ++f_)
                acc[mf][s_][f_] = MFMA(a, X[s_][f_], acc[mf][s_][f_], 0, 0, 0);
          }
        }
        __syncthreads();                   // x consumed
        stage_st(); __syncthreads();       // Abuf <- h0 chunk0
        stage_ld(h0rd, 256); LDW(1, 1); CHUNK(0); __syncthreads();
        stage_st(); __syncthreads();
        stage_ld(h0rd, 512); LDW(0, 2); CHUNK(1); __syncthreads();
        stage_st(); __syncthreads();
        stage_ld(h0rd, 768); LDW(1, 3); CHUNK(0); __syncthreads();
        stage_st(); __syncthreads();
        CHUNK(1);
        reduce2();
        ew(h0wr, false);
      }
      gridbar(t);
    }
  } else {
    // -------------- layer-1 WGs: compute h1(t-1) each phase --------------
#pragma unroll 1
    for (int t = 0; t <= 512; ++t) {
      if (t >= 1) {
        cache_inv();                       // kill stale h lines from t-2 reads
        const u16* h0rd = h0b + ((t + 1) & 1) * HB;   // h0(t-1)
        const u16* h1rd = h1b + (t & 1) * HB;         // h1(t-2)
        u16* h1wr = h1b + ((t + 1) & 1) * HB;         // h1(t-1)
        acc_init();
        stage_ld(h0rd, 0); LDW(0, 0);
        stage_st(); __syncthreads();
        stage_ld(h0rd, 256); LDW(1, 1); CHUNK(0); __syncthreads();
        stage_st(); __syncthreads();
        stage_ld(h0rd, 512); LDW(0, 2); CHUNK(1); __syncthreads();
        stage_st(); __syncthreads();
        stage_ld(h0rd, 768); LDW(1, 3); CHUNK(0); __syncthreads();
        stage_st(); __syncthreads();
        stage_ld(h1rd, 0);   LDW(0, 4); CHUNK(1); __syncthreads();
        stage_st(); __syncthreads();
        stage_ld(h1rd, 256); LDW(1, 5); CHUNK(0); __syncthreads();
        stage_st(); __syncthreads();
        stage_ld(h1rd, 512); LDW(0, 6); CHUNK(1); __syncthreads();
        stage_st(); __syncthreads();
        stage_ld(h1rd, 768); LDW(1, 7); CHUNK(0); __syncthreads();
        stage_st(); __syncthreads();
        CHUNK(1);
        reduce2();
        ew(h1wr, t == 512);
      }
      gridbar(t);
    }
  }

  // ---------------- fc epilogue: out = h1(511) @ fcW.T + fcb ----------------
  if (blk < 64) {
    const int row = (blk << 2) | w;
    const float* hrow = h1f + ((size_t)row << 10);
#pragma unroll 1
    for (int o = 0; o < 12; ++o) {
      const float* wrow = fcW + o * 1024;
      float p = 0.f;
#pragma unroll
      for (int j = 0; j < 16; ++j) {
        int k = (j << 6) | lane;
        p += __builtin_nontemporal_load(hrow + k) * wrow[k];
      }
#pragma unroll
      for (int off = 32; off > 0; off >>= 1) p += __shfl_down(p, off, 64);
      if (lane == 0) out[row * 12 + o] = p + fcb[o];
    }
  }
}

extern "C" void kernel_launch(void* const* d_in, const int* in_sizes, int n_in,
                              void* d_out, int out_size, void* d_ws, size_t ws_size,
                              hipStream_t stream) {
  (void)in_sizes; (void)n_in; (void)out_size; (void)ws_size;
  const float* x   = (const float*)d_in[0];
  const float* Wx0 = (const float*)d_in[1];
  const float* Wh0 = (const float*)d_in[2];
  const float* b0  = (const float*)d_in[3];
  const float* Wx1 = (const float*)d_in[4];
  const float* Wh1 = (const float*)d_in[5];
  const float* b1  = (const float*)d_in[6];
  const float* fcW = (const float*)d_in[7];
  const float* fcb = (const float*)d_in[8];

  char* ws = (char*)d_ws;
  u16* W1p   = (u16*)ws;                          // 16 MiB packed Wx1|Wh1
  u16* W0p   = (u16*)(ws + (16u << 20));          //  8 MiB packed Wh0
  u16* X0p   = (u16*)(ws + (24u << 20));          // 512 KiB packed Wx0
  u16* h0b   = (u16*)(ws + (25u << 20));          // 2 x 512 KiB
  u16* h1b   = (u16*)(ws + (26u << 20));          // 2 x 512 KiB
  float* h1f = (float*)(ws + (27u << 20));        // 1 MiB
  u32* bar   = (u32*)(ws + (28u << 20));          // counters

  hipMemsetAsync(ws + (25u << 20) + (1 << 19), 0, 1 << 19, stream);  // h0b[1]
  hipMemsetAsync(ws + (26u << 20) + (1 << 19), 0, 1 << 19, stream);  // h1b[1]
  hipMemsetAsync(bar, 0, 4096, stream);

  wconv<<<6272, 256, 0, stream>>>(Wx0, Wh0, Wx1, Wh1, W1p, W0p, X0p);
  lstm_persist<<<512, 256, 0, stream>>>(x, b0, b1, fcW, fcb,
                                        W1p, W0p, X0p,
                                        h0b, h1b, h1f, bar, (float*)d_out);
}

// Round 11
// 12344.764 us; speedup vs baseline: 1.1375x; 1.1375x over previous
//
#include <hip/hip_runtime.h>

// ============================================================================
// 2-layer LSTM, persistent kernel, MI355X — round 11 (no-LDS-staging).
// Insight: with the kway k-split, h has ZERO intra-WG reuse — every element
// feeds exactly one lane's A-fragment, which is 16 CONTIGUOUS bytes at a
// per-lane global address. The whole Abuf/stage/barrier machinery (19
// syncs/phase, per-chunk vmcnt drains, 2.4e8 bank conflicts) staged data
// nobody shared. R11 loads A-fragments DIRECTLY global->reg (nt, LLC):
//   * per tick: LDA(c+1) + LDW(c+1) issue, CHUNK(c) on regs loaded last tick
//     (double-banked A and W -> MFMA never waits on newer FIFO entries);
//   * sched_barrier(0) at tick boundaries pins the pipeline (anti-hoist);
//   * ZERO intra-phase barriers; 8 independent waves/CU hide LLC latency;
//   * LDS = gA/gB/cbuf only (39KB).
// R8/R9/R10 lessons honored: W stays double-banked (FIFO), no buffer_inv
// (weights stay L2), h loads stay nt + h stores stay sc01 (proven coherent).
// reduce2/ew/gridbar/wconv/x-tick verbatim R7 (8.45 ms, absmax 4.9e-3).
// ============================================================================

typedef unsigned int u32;
typedef unsigned short u16;
typedef __attribute__((ext_vector_type(8))) short bf16x8;
typedef __attribute__((ext_vector_type(4))) float f32x4;

#define MFMA __builtin_amdgcn_mfma_f32_16x16x32_bf16
#define HB (256 * 1024)   // h buffer elems per parity
#define SCHED0 __builtin_amdgcn_sched_barrier(0)

__device__ __forceinline__ u16 f2bf(float f) {
  u32 u = __float_as_uint(f);
  u += 0x7fffu + ((u >> 16) & 1u);   // RNE (inputs finite)
  return (u16)(u >> 16);
}
__device__ __forceinline__ float sigm(float v) { return 1.f / (1.f + __expf(-v)); }
__device__ __forceinline__ float tanh_(float v) { return 1.f - 2.f / (__expf(2.f * v) + 1.f); }

__device__ __forceinline__ u32 ld_u32_sc01(const u32* p) {
  u32 v;
  asm volatile("global_load_dword %0, %1, off sc0 sc1\n\ts_waitcnt vmcnt(0)"
               : "=v"(v) : "v"(p) : "memory");
  return v;
}
__device__ __forceinline__ void st_u32_sc01(u32* p, u32 v) {
  asm volatile("global_store_dword %0, %1, off sc0 sc1" :: "v"(p), "v"(v) : "memory");
}
__device__ __forceinline__ void st_f32_sc01(float* p, float v) {
  asm volatile("global_store_dword %0, %1, off sc0 sc1" :: "v"(p), "v"(v) : "memory");
}

// ---------------- prologue: f32 -> bf16 packed-fragment weights ----------------
// (verbatim from R7)
__global__ void __launch_bounds__(256) wconv(
    const float* __restrict__ Wx0, const float* __restrict__ Wh0,
    const float* __restrict__ Wx1, const float* __restrict__ Wh1,
    u16* __restrict__ W1p, u16* __restrict__ W0p, u16* __restrict__ X0p) {
  const u32 NG1 = 1048576u, NG0 = 524288u, NGX = 32768u;
  u32 g = blockIdx.x * 256u + threadIdx.x;
  const float* src; u16* dst;
  if (g < NG1) {
    u32 lane = g & 63u, f = (g >> 6) & 1u, jj = (g >> 7) & 1u, c = (g >> 8) & 7u;
    u32 kway = (g >> 11) & 3u, s = (g >> 13) & 1u, u0idx = g >> 14;
    u32 i15 = lane & 15u, kq = lane >> 4;
    u32 row = (2u * f + (i15 >> 3)) * 1024u + u0idx * 16u + s * 8u + (i15 & 7u);
    u32 k = (kway + 4u * (2u * c + jj)) * 32u + kq * 8u;
    src = (k < 1024u) ? Wx1 + (size_t)row * 1024 + k
                      : Wh1 + (size_t)row * 1024 + (k - 1024u);
    dst = W1p + (size_t)g * 8;
  } else if (g < NG1 + NG0) {
    u32 h = g - NG1;
    u32 lane = h & 63u, f = (h >> 6) & 1u, jj = (h >> 7) & 1u, c = (h >> 8) & 3u;
    u32 kway = (h >> 10) & 3u, s = (h >> 12) & 1u, u0idx = h >> 13;
    u32 i15 = lane & 15u, kq = lane >> 4;
    u32 row = (2u * f + (i15 >> 3)) * 1024u + u0idx * 16u + s * 8u + (i15 & 7u);
    u32 k = (kway + 4u * (2u * c + jj)) * 32u + kq * 8u;
    src = Wh0 + (size_t)row * 1024 + k;
    dst = W0p + (size_t)h * 8;
  } else if (g < NG1 + NG0 + NGX) {
    u32 h = g - NG1 - NG0;
    u32 lane = h & 63u, f = (h >> 6) & 1u, kway = (h >> 7) & 1u;
    u32 s = (h >> 8) & 1u, u0idx = h >> 9;
    u32 i15 = lane & 15u, kq = lane >> 4;
    u32 row = (2u * f + (i15 >> 3)) * 1024u + u0idx * 16u + s * 8u + (i15 & 7u);
    u32 k = kway * 32u + kq * 8u;
    src = Wx0 + (size_t)row * 64 + k;
    dst = X0p + (size_t)h * 8;
  } else return;
  float4 v0 = *(const float4*)src, v1 = *(const float4*)(src + 4);
  bf16x8 r;
  r[0] = (short)f2bf(v0.x); r[1] = (short)f2bf(v0.y);
  r[2] = (short)f2bf(v0.z); r[3] = (short)f2bf(v0.w);
  r[4] = (short)f2bf(v1.x); r[5] = (short)f2bf(v1.y);
  r[6] = (short)f2bf(v1.z); r[7] = (short)f2bf(v1.w);
  *(bf16x8*)dst = r;
}

// ---- weight load: double-banked, per-call opaque offset (verbatim R7) ----
#define LDW(bank, c) do {                                                      \
  u32 o0_ = bW[0] + (u32)((c) * 2048), o1_ = bW[1] + (u32)((c) * 2048);        \
  asm volatile("" : "+v"(o0_), "+v"(o1_));                                     \
  _Pragma("unroll")                                                            \
  for (int jj_ = 0; jj_ < 2; ++jj_)                                            \
    _Pragma("unroll")                                                          \
    for (int f_ = 0; f_ < 2; ++f_) {                                           \
      W[bank][jj_][0][f_] = *(const bf16x8*)(WP + o0_ + (u32)(jj_*1024+f_*512));\
      W[bank][jj_][1][f_] = *(const bf16x8*)(WP + o1_ + (u32)(jj_*1024+f_*512));\
    }                                                                          \
} while (0)

// ---- A-fragment load: DIRECT global->reg (nt), double-banked ----
// cb = chunk byte offset within parity buffer's row (c_local*512)
#define LDA(bank, srcp, cb) do {                                               \
  u32 ob_ = (u32)(cb);                                                         \
  asm volatile("" : "+v"(ob_));                                                \
  const char* p_ = (const char*)(srcp);                                        \
  _Pragma("unroll")                                                            \
  for (int jj_ = 0; jj_ < 2; ++jj_)                                            \
    _Pragma("unroll")                                                          \
    for (int mf_ = 0; mf_ < 4; ++mf_)                                          \
      Ab[bank][jj_][mf_] = __builtin_nontemporal_load(                         \
        (const bf16x8*)(p_ + aoffb[mf_] + ob_ + (u32)(jj_ * 256)));            \
} while (0)

// ---- per-chunk MFMA: 2 jj x 4 mf x 4 (s,f) = 32 MFMA, regs only ----
#define CHUNK(bank) do {                                                       \
  _Pragma("unroll")                                                            \
  for (int jj_ = 0; jj_ < 2; ++jj_)                                            \
    _Pragma("unroll")                                                          \
    for (int mf_ = 0; mf_ < 4; ++mf_) {                                        \
      bf16x8 a_ = Ab[bank][jj_][mf_];                                          \
      _Pragma("unroll")                                                        \
      for (int s_ = 0; s_ < 2; ++s_)                                           \
        _Pragma("unroll")                                                      \
        for (int f_ = 0; f_ < 2; ++f_)                                         \
          acc[mf_][s_][f_] = MFMA(a_, W[bank][jj_][s_][f_],                    \
                                  acc[mf_][s_][f_], 0, 0, 0);                  \
    }                                                                          \
} while (0)

__global__ void __launch_bounds__(256, 2)
lstm_persist(const float* __restrict__ x,
             const float* __restrict__ b0, const float* __restrict__ b1,
             const float* __restrict__ fcW, const float* __restrict__ fcb,
             const u16* __restrict__ W1p, const u16* __restrict__ W0p,
             const u16* __restrict__ X0p,
             u16* __restrict__ h0b, u16* __restrict__ h1b,
             float* __restrict__ h1f, u32* __restrict__ bar,
             float* __restrict__ out)
{
  const int tid = threadIdx.x, blk = blockIdx.x;
  const int lane = tid & 63, w = tid >> 6;
  const int kway = w;                 // wave = k-split lane (0..3)
  const int L = blk >> 8;             // 0: layer0 WG, 1: layer1 WG
  const int sub = blk & 255;
  const int m0 = (sub >> 6) << 6;     // batch tile base
  const int u0idx = sub & 63;
  const int u0 = u0idx << 4;          // hidden-unit base

  __shared__ float gA[64][68];        // k-reduce region A
  __shared__ float gB[64][68];        // k-reduce region B
  __shared__ float cbuf[64][16];      // persistent c state (own layer)

  for (int i = tid; i < 64 * 16; i += 256) ((float*)cbuf)[i] = 0.f;

  const int i15 = lane & 15, kq = lane >> 4;

  // packed-weight base offsets (u32 elem offsets; verbatim R7)
  u32 bW[2], bX[2];
#pragma unroll
  for (int s_ = 0; s_ < 2; ++s_) {
    u32 key = (u32)((u0idx << 1) | s_);
    bW[s_] = ((key << 2) | (u32)kway) * (L ? 16384u : 8192u) + (u32)lane * 8u;
    bX[s_] = ((key << 1) | (u32)kway) * 1024u + (u32)lane * 8u;  // kway<2 only
  }
  const u16* WP = L ? W1p : W0p;

  float bias[2][2];
#pragma unroll
  for (int s_ = 0; s_ < 2; ++s_)
#pragma unroll
    for (int f_ = 0; f_ < 2; ++f_) {
      int rowf = ((f_ << 1) + (i15 >> 3)) * 1024 + u0 + s_ * 8 + (i15 & 7);
      bias[s_][f_] = (kway == 0) ? (L ? b1[rowf] : b0[rowf]) : 0.f;
    }

  // per-lane A-fragment byte offsets (per mf) into an h parity buffer
  u32 aoffb[4];
#pragma unroll
  for (int mf = 0; mf < 4; ++mf)
    aoffb[mf] = (u32)(((((m0 + (mf << 4) + i15) << 10) + (kway << 5) + (kq << 3)) << 1));

  bf16x8 Ab[2][2][4];     // [bank][jj][mf] A fragments (64 regs)
  bf16x8 W[2][2][2][2];   // [bank][jj][s][f] weights (64 regs)
  f32x4 acc[4][2][2];     // [mf][s][f] (64 regs)

  auto acc_init = [&]() {
#pragma unroll
    for (int mf = 0; mf < 4; ++mf)
#pragma unroll
      for (int s_ = 0; s_ < 2; ++s_)
#pragma unroll
        for (int f_ = 0; f_ < 2; ++f_) {
          float bv = bias[s_][f_];
          acc[mf][s_][f_][0] = bv; acc[mf][s_][f_][1] = bv;
          acc[mf][s_][f_][2] = bv; acc[mf][s_][f_][3] = bv;
        }
  };

  auto reduce2 = [&]() {   // 4 kway partials -> gA + gB (verbatim R7)
    if (kway < 2) {
      float (*g)[68] = kway ? gB : gA;
#pragma unroll
      for (int mf = 0; mf < 4; ++mf)
#pragma unroll
        for (int s_ = 0; s_ < 2; ++s_)
#pragma unroll
          for (int f_ = 0; f_ < 2; ++f_)
#pragma unroll
            for (int r = 0; r < 4; ++r)
              g[(mf << 4) + (kq << 2) + r][(s_ << 5) + (f_ << 4) + i15] = acc[mf][s_][f_][r];
    }
    __syncthreads();
    if (kway >= 2) {
      float (*g)[68] = (kway == 3) ? gB : gA;
#pragma unroll
      for (int mf = 0; mf < 4; ++mf)
#pragma unroll
        for (int s_ = 0; s_ < 2; ++s_)
#pragma unroll
          for (int f_ = 0; f_ < 2; ++f_)
#pragma unroll
            for (int r = 0; r < 4; ++r)
              g[(mf << 4) + (kq << 2) + r][(s_ << 5) + (f_ << 4) + i15] += acc[mf][s_][f_][r];
    }
    __syncthreads();
  };

  auto ew = [&](u16* hdst, bool wf32) {   // verbatim R7
    int row = tid >> 2, un = (tid & 3) << 2;
    float hq[4];
#pragma unroll
    for (int q = 0; q < 4; ++q) {
      int u = un + q;
      int cb = ((u >> 3) << 5) | (u & 7);
      float gi = gA[row][cb]      + gB[row][cb];
      float gf = gA[row][cb + 8]  + gB[row][cb + 8];
      float gg = gA[row][cb + 16] + gB[row][cb + 16];
      float go = gA[row][cb + 24] + gB[row][cb + 24];
      float ii = sigm(gi), ff = sigm(gf), g2 = tanh_(gg), oo = sigm(go);
      float c = ff * cbuf[row][u] + ii * g2;
      cbuf[row][u] = c;
      hq[q] = oo * tanh_(c);
    }
    size_t idx = ((size_t)(m0 + row) << 10) + u0 + un;
    st_u32_sc01((u32*)(hdst + idx),     (u32)f2bf(hq[0]) | ((u32)f2bf(hq[1]) << 16));
    st_u32_sc01((u32*)(hdst + idx + 2), (u32)f2bf(hq[2]) | ((u32)f2bf(hq[3]) << 16));
    if (wf32) {
      st_f32_sc01(h1f + idx,     hq[0]); st_f32_sc01(h1f + idx + 1, hq[1]);
      st_f32_sc01(h1f + idx + 2, hq[2]); st_f32_sc01(h1f + idx + 3, hq[3]);
    }
  };

  auto gridbar = [&](int t) {       // verbatim R7 leader-tree barrier
    __syncthreads();                // drains vmcnt -> sc01 h stores at LLC
    if (tid == 0) {
      const int g = blk & 7;
      u32* gc   = bar + g * 32;
      u32* root = bar + 256;
      u32* gen  = bar + 288 + g * 32;
      const u32 p1 = (u32)(t + 1);
      __hip_atomic_fetch_add(gc, 1u, __ATOMIC_RELAXED, __HIP_MEMORY_SCOPE_AGENT);
      if (blk < 8) {
        while (ld_u32_sc01(gc) < 64u * p1) __builtin_amdgcn_s_sleep(4);
        __hip_atomic_fetch_add(root, 1u, __ATOMIC_RELAXED, __HIP_MEMORY_SCOPE_AGENT);
        while (ld_u32_sc01(root) < 8u * p1) __builtin_amdgcn_s_sleep(2);
        st_u32_sc01(gen, p1);
      } else {
        while (ld_u32_sc01(gen) < p1) __builtin_amdgcn_s_sleep(4);
      }
    }
    __syncthreads();
  };

  if (L == 0) {
    // ---------------- layer-0 WGs: compute h0(t) each phase ----------------
#pragma unroll 1
    for (int t = 0; t <= 512; ++t) {
      if (t < 512) {
        const u16* h0rd = h0b + ((t + 1) & 1) * HB;
        u16* h0wr = h0b + (t & 1) * HB;
        acc_init();
        LDA(0, h0rd, 0); LDW(0, 0);        // chunk0 in flight (LLC+L2)
        // x-frag direct loads + X weights + x-tick (kway<2), hides chunk0 lat
        if (kway < 2) {
          const char* xt = (const char*)x + (size_t)m0 * 131072u + (size_t)t * 256u;
          const u32 oxw = (u32)(((kway << 5) + (kq << 3)) << 2);
          bf16x8 ax[4];
#pragma unroll
          for (int mf = 0; mf < 4; ++mf) {
            const float* g = (const float*)(xt + (size_t)((mf << 4) + i15) * 131072u + oxw);
            float4 a0 = *(const float4*)g, a1 = *(const float4*)(g + 4);
            bf16x8 r;
            r[0] = (short)f2bf(a0.x); r[1] = (short)f2bf(a0.y);
            r[2] = (short)f2bf(a0.z); r[3] = (short)f2bf(a0.w);
            r[4] = (short)f2bf(a1.x); r[5] = (short)f2bf(a1.y);
            r[6] = (short)f2bf(a1.z); r[7] = (short)f2bf(a1.w);
            ax[mf] = r;
          }
          u32 ox0 = bX[0], ox1 = bX[1];
          asm volatile("" : "+v"(ox0), "+v"(ox1));
          bf16x8 X00 = *(const bf16x8*)(X0p + ox0);
          bf16x8 X01 = *(const bf16x8*)(X0p + ox0 + 512u);
          bf16x8 X10 = *(const bf16x8*)(X0p + ox1);
          bf16x8 X11 = *(const bf16x8*)(X0p + ox1 + 512u);
#pragma unroll
          for (int mf = 0; mf < 4; ++mf) {
            acc[mf][0][0] = MFMA(ax[mf], X00, acc[mf][0][0], 0, 0, 0);
            acc[mf][0][1] = MFMA(ax[mf], X01, acc[mf][0][1], 0, 0, 0);
            acc[mf][1][0] = MFMA(ax[mf], X10, acc[mf][1][0], 0, 0, 0);
            acc[mf][1][1] = MFMA(ax[mf], X11, acc[mf][1][1], 0, 0, 0);
          }
        }
        SCHED0;
        LDA(1, h0rd, 512);  LDW(1, 1); CHUNK(0); SCHED0;
        LDA(0, h0rd, 1024); LDW(0, 2); CHUNK(1); SCHED0;
        LDA(1, h0rd, 1536); LDW(1, 3); CHUNK(0); SCHED0;
        CHUNK(1);
        reduce2();
        ew(h0wr, false);
      }
      gridbar(t);
    }
  } else {
    // -------------- layer-1 WGs: compute h1(t-1) each phase --------------
#pragma unroll 1
    for (int t = 0; t <= 512; ++t) {
      if (t >= 1) {
        const u16* h0rd = h0b + ((t + 1) & 1) * HB;   // h0(t-1)
        const u16* h1rd = h1b + (t & 1) * HB;         // h1(t-2)
        u16* h1wr = h1b + ((t + 1) & 1) * HB;         // h1(t-1)
        acc_init();
        LDA(0, h0rd, 0);    LDW(0, 0); SCHED0;
        LDA(1, h0rd, 512);  LDW(1, 1); CHUNK(0); SCHED0;
        LDA(0, h0rd, 1024); LDW(0, 2); CHUNK(1); SCHED0;
        LDA(1, h0rd, 1536); LDW(1, 3); CHUNK(0); SCHED0;
        LDA(0, h1rd, 0);    LDW(0, 4); CHUNK(1); SCHED0;
        LDA(1, h1rd, 512);  LDW(1, 5); CHUNK(0); SCHED0;
        LDA(0, h1rd, 1024); LDW(0, 6); CHUNK(1); SCHED0;
        LDA(1, h1rd, 1536); LDW(1, 7); CHUNK(0); SCHED0;
        CHUNK(1);
        reduce2();
        ew(h1wr, t == 512);
      }
      gridbar(t);
    }
  }

  // ---------------- fc epilogue (verbatim R7) ----------------
  if (blk < 64) {
    const int row = (blk << 2) | w;
    const float* hrow = h1f + ((size_t)row << 10);
#pragma unroll 1
    for (int o = 0; o < 12; ++o) {
      const float* wrow = fcW + o * 1024;
      float p = 0.f;
#pragma unroll
      for (int j = 0; j < 16; ++j) {
        int k = (j << 6) | lane;
        p += __builtin_nontemporal_load(hrow + k) * wrow[k];
      }
#pragma unroll
      for (int off = 32; off > 0; off >>= 1) p += __shfl_down(p, off, 64);
      if (lane == 0) out[row * 12 + o] = p + fcb[o];
    }
  }
}

extern "C" void kernel_launch(void* const* d_in, const int* in_sizes, int n_in,
                              void* d_out, int out_size, void* d_ws, size_t ws_size,
                              hipStream_t stream) {
  (void)in_sizes; (void)n_in; (void)out_size; (void)ws_size;
  const float* x   = (const float*)d_in[0];
  const float* Wx0 = (const float*)d_in[1];
  const float* Wh0 = (const float*)d_in[2];
  const float* b0  = (const float*)d_in[3];
  const float* Wx1 = (const float*)d_in[4];
  const float* Wh1 = (const float*)d_in[5];
  const float* b1  = (const float*)d_in[6];
  const float* fcW = (const float*)d_in[7];
  const float* fcb = (const float*)d_in[8];

  char* ws = (char*)d_ws;
  u16* W1p   = (u16*)ws;                          // 16 MiB packed Wx1|Wh1
  u16* W0p   = (u16*)(ws + (16u << 20));          //  8 MiB packed Wh0
  u16* X0p   = (u16*)(ws + (24u << 20));          // 512 KiB packed Wx0
  u16* h0b   = (u16*)(ws + (25u << 20));          // 2 x 512 KiB
  u16* h1b   = (u16*)(ws + (26u << 20));          // 2 x 512 KiB
  float* h1f = (float*)(ws + (27u << 20));        // 1 MiB
  u32* bar   = (u32*)(ws + (28u << 20));          // counters

  hipMemsetAsync(ws + (25u << 20) + (1 << 19), 0, 1 << 19, stream);  // h0b[1]
  hipMemsetAsync(ws + (26u << 20) + (1 << 19), 0, 1 << 19, stream);  // h1b[1]
  hipMemsetAsync(bar, 0, 4096, stream);

  wconv<<<6272, 256, 0, stream>>>(Wx0, Wh0, Wx1, Wh1, W1p, W0p, X0p);
  lstm_persist<<<512, 256, 0, stream>>>(x, b0, b1, fcW, fcb,
                                        W1p, W0p, X0p,
                                        h0b, h1b, h1f, bar, (float*)d_out);
}

// Round 12
// 11170.468 us; speedup vs baseline: 1.2570x; 1.1051x over previous
//
#include <hip/hip_runtime.h>

// ============================================================================
// 2-layer LSTM, persistent kernel, MI355X — round 12 (fused layers, m32).
// Diagnosis across R7/R8/R11: all land at effective LLC h-read ~5.5-6 TB/s ->
// R7 (best, 8.45 ms) is LLC-BANDWIDTH-bound on h re-reads (96 MB/phase;
// coherence forces h through LLC via sc01-store/nt-load). Lever = traffic.
// R12: ONE fused WG class: 512 WGs = 8 m-tiles(32 rows) x 64 u-tiles(16 units),
// each computes L0(t) AND L1(t-1). Every staged h0 chunk feeds BOTH Wh0 (L0)
// and the Wx1 half of W1 (L1): h0 read once per WG -> 64 MB/phase (0.67x).
// Verbatim from R7 (proven 7x, absmax 4.9e-3): wconv packing (keyed by u0idx,
// unchanged), bW/LDW offsets, 2-sync staging windows + XOR swizzle, kway
// k-split + reduce2 (now both layers in one pass), ew math, sc01 h stores,
// nt h loads, leader-tree grid barrier. W0 single-banked, loaded AFTER
// CHUNK0 (WAR-safe; latency hidden under CHUNK1+sync) to stay in register
// budget: acc 64 + W1 dbuf 64 + W0 32 + v 16 ~= 230 unified.
// ============================================================================

typedef unsigned int u32;
typedef unsigned short u16;
typedef __attribute__((ext_vector_type(8))) short bf16x8;
typedef __attribute__((ext_vector_type(4))) float f32x4;

#define MFMA __builtin_amdgcn_mfma_f32_16x16x32_bf16
#define HB (256 * 1024)   // h buffer elems per parity

__device__ __forceinline__ u16 f2bf(float f) {
  u32 u = __float_as_uint(f);
  u += 0x7fffu + ((u >> 16) & 1u);   // RNE (inputs finite)
  return (u16)(u >> 16);
}
__device__ __forceinline__ float sigm(float v) { return 1.f / (1.f + __expf(-v)); }
__device__ __forceinline__ float tanh_(float v) { return 1.f - 2.f / (__expf(2.f * v) + 1.f); }

__device__ __forceinline__ u32 ld_u32_sc01(const u32* p) {
  u32 v;
  asm volatile("global_load_dword %0, %1, off sc0 sc1\n\ts_waitcnt vmcnt(0)"
               : "=v"(v) : "v"(p) : "memory");
  return v;
}
__device__ __forceinline__ void st_u32_sc01(u32* p, u32 v) {
  asm volatile("global_store_dword %0, %1, off sc0 sc1" :: "v"(p), "v"(v) : "memory");
}
__device__ __forceinline__ void st_f32_sc01(float* p, float v) {
  asm volatile("global_store_dword %0, %1, off sc0 sc1" :: "v"(p), "v"(v) : "memory");
}

// ---------------- prologue: f32 -> bf16 packed-fragment weights ----------------
// (verbatim from R7)
__global__ void __launch_bounds__(256) wconv(
    const float* __restrict__ Wx0, const float* __restrict__ Wh0,
    const float* __restrict__ Wx1, const float* __restrict__ Wh1,
    u16* __restrict__ W1p, u16* __restrict__ W0p, u16* __restrict__ X0p) {
  const u32 NG1 = 1048576u, NG0 = 524288u, NGX = 32768u;
  u32 g = blockIdx.x * 256u + threadIdx.x;
  const float* src; u16* dst;
  if (g < NG1) {
    u32 lane = g & 63u, f = (g >> 6) & 1u, jj = (g >> 7) & 1u, c = (g >> 8) & 7u;
    u32 kway = (g >> 11) & 3u, s = (g >> 13) & 1u, u0idx = g >> 14;
    u32 i15 = lane & 15u, kq = lane >> 4;
    u32 row = (2u * f + (i15 >> 3)) * 1024u + u0idx * 16u + s * 8u + (i15 & 7u);
    u32 k = (kway + 4u * (2u * c + jj)) * 32u + kq * 8u;
    src = (k < 1024u) ? Wx1 + (size_t)row * 1024 + k
                      : Wh1 + (size_t)row * 1024 + (k - 1024u);
    dst = W1p + (size_t)g * 8;
  } else if (g < NG1 + NG0) {
    u32 h = g - NG1;
    u32 lane = h & 63u, f = (h >> 6) & 1u, jj = (h >> 7) & 1u, c = (h >> 8) & 3u;
    u32 kway = (h >> 10) & 3u, s = (h >> 12) & 1u, u0idx = h >> 13;
    u32 i15 = lane & 15u, kq = lane >> 4;
    u32 row = (2u * f + (i15 >> 3)) * 1024u + u0idx * 16u + s * 8u + (i15 & 7u);
    u32 k = (kway + 4u * (2u * c + jj)) * 32u + kq * 8u;
    src = Wh0 + (size_t)row * 1024 + k;
    dst = W0p + (size_t)h * 8;
  } else if (g < NG1 + NG0 + NGX) {
    u32 h = g - NG1 - NG0;
    u32 lane = h & 63u, f = (h >> 6) & 1u, kway = (h >> 7) & 1u;
    u32 s = (h >> 8) & 1u, u0idx = h >> 9;
    u32 i15 = lane & 15u, kq = lane >> 4;
    u32 row = (2u * f + (i15 >> 3)) * 1024u + u0idx * 16u + s * 8u + (i15 & 7u);
    u32 k = kway * 32u + kq * 8u;
    src = Wx0 + (size_t)row * 64 + k;
    dst = X0p + (size_t)h * 8;
  } else return;
  float4 v0 = *(const float4*)src, v1 = *(const float4*)(src + 4);
  bf16x8 r;
  r[0] = (short)f2bf(v0.x); r[1] = (short)f2bf(v0.y);
  r[2] = (short)f2bf(v0.z); r[3] = (short)f2bf(v0.w);
  r[4] = (short)f2bf(v1.x); r[5] = (short)f2bf(v1.y);
  r[6] = (short)f2bf(v1.z); r[7] = (short)f2bf(v1.w);
  *(bf16x8*)dst = r;
}

// ---- weight loads: W1 double-banked, W0 single-bank (per-call opaque) ----
#define LDW1(bank, c) do {                                                     \
  u32 o0_ = bW1[0] + (u32)((c) * 2048), o1_ = bW1[1] + (u32)((c) * 2048);      \
  asm volatile("" : "+v"(o0_), "+v"(o1_));                                     \
  _Pragma("unroll")                                                            \
  for (int jj_ = 0; jj_ < 2; ++jj_)                                            \
    _Pragma("unroll")                                                          \
    for (int f_ = 0; f_ < 2; ++f_) {                                           \
      W1[bank][jj_][0][f_] = *(const bf16x8*)(W1p + o0_ + (u32)(jj_*1024+f_*512));\
      W1[bank][jj_][1][f_] = *(const bf16x8*)(W1p + o1_ + (u32)(jj_*1024+f_*512));\
    }                                                                          \
} while (0)

#define LDW0(c) do {                                                           \
  u32 o0_ = bW0[0] + (u32)((c) * 2048), o1_ = bW0[1] + (u32)((c) * 2048);      \
  asm volatile("" : "+v"(o0_), "+v"(o1_));                                     \
  _Pragma("unroll")                                                            \
  for (int jj_ = 0; jj_ < 2; ++jj_)                                            \
    _Pragma("unroll")                                                          \
    for (int f_ = 0; f_ < 2; ++f_) {                                           \
      W0[jj_][0][f_] = *(const bf16x8*)(W0p + o0_ + (u32)(jj_*1024+f_*512));   \
      W0[jj_][1][f_] = *(const bf16x8*)(W0p + o1_ + (u32)(jj_*1024+f_*512));   \
    }                                                                          \
} while (0)

// ---- per-chunk MFMA: 2 jj x 2 mf x 4 (s,f) = 16 MFMA per layer ----
#define CHUNK0() do {                                                          \
  _Pragma("unroll")                                                            \
  for (int jj_ = 0; jj_ < 2; ++jj_) {                                          \
    const int kin_ = (kway + (jj_ << 2)) << 5;                                 \
    _Pragma("unroll")                                                          \
    for (int mf_ = 0; mf_ < 2; ++mf_) {                                        \
      bf16x8 a_ = readA(mf_, kin_);                                            \
      _Pragma("unroll")                                                        \
      for (int s_ = 0; s_ < 2; ++s_)                                           \
        _Pragma("unroll")                                                      \
        for (int f_ = 0; f_ < 2; ++f_)                                         \
          acc0[mf_][s_][f_] = MFMA(a_, W0[jj_][s_][f_], acc0[mf_][s_][f_],0,0,0);\
    }                                                                          \
  }                                                                            \
} while (0)

#define CHUNK1(bank) do {                                                      \
  _Pragma("unroll")                                                            \
  for (int jj_ = 0; jj_ < 2; ++jj_) {                                          \
    const int kin_ = (kway + (jj_ << 2)) << 5;                                 \
    _Pragma("unroll")                                                          \
    for (int mf_ = 0; mf_ < 2; ++mf_) {                                        \
      bf16x8 a_ = readA(mf_, kin_);                                            \
      _Pragma("unroll")                                                        \
      for (int s_ = 0; s_ < 2; ++s_)                                           \
        _Pragma("unroll")                                                      \
        for (int f_ = 0; f_ < 2; ++f_)                                         \
          acc1[mf_][s_][f_] = MFMA(a_, W1[bank][jj_][s_][f_],                  \
                                   acc1[mf_][s_][f_], 0, 0, 0);                \
    }                                                                          \
  }                                                                            \
} while (0)

__global__ void __launch_bounds__(256, 2)
lstm_persist(const float* __restrict__ x,
             const float* __restrict__ b0, const float* __restrict__ b1,
             const float* __restrict__ fcW, const float* __restrict__ fcb,
             const u16* __restrict__ W1p, const u16* __restrict__ W0p,
             const u16* __restrict__ X0p,
             u16* __restrict__ h0b, u16* __restrict__ h1b,
             float* __restrict__ h1f, u32* __restrict__ bar,
             float* __restrict__ out)
{
  const int tid = threadIdx.x, blk = blockIdx.x;
  const int lane = tid & 63, w = tid >> 6;
  const int kway = w;                 // wave = k-split lane (0..3)
  const int mtile = blk >> 6;         // 0..7 (m32 tiles)
  const int u0idx = blk & 63;         // XCD = blk%8 = u0idx%8 -> weights L2-resident
  const int m0 = mtile << 5;
  const int u0 = u0idx << 4;

  __shared__ short Abuf[32 * 256];    // 16KB staged A chunk (m32 x K256)
  __shared__ float G[2][2][32][68];   // [layer][AB][row][col] k-reduce regions
  __shared__ float cbuf[2][32][16];   // persistent c state, both layers

  for (int i = tid; i < 2 * 32 * 16; i += 256) ((float*)cbuf)[i] = 0.f;

  const int i15 = lane & 15, kq = lane >> 4;

  // packed-weight base offsets (verbatim R7 formulas)
  u32 bW1[2], bW0[2], bX[2];
#pragma unroll
  for (int s_ = 0; s_ < 2; ++s_) {
    u32 key = (u32)((u0idx << 1) | s_);
    bW1[s_] = ((key << 2) | (u32)kway) * 16384u + (u32)lane * 8u;
    bW0[s_] = ((key << 2) | (u32)kway) * 8192u  + (u32)lane * 8u;
    bX[s_]  = ((key << 1) | (u32)kway) * 1024u  + (u32)lane * 8u;  // kway<2
  }

  float bias0[2][2], bias1[2][2];
#pragma unroll
  for (int s_ = 0; s_ < 2; ++s_)
#pragma unroll
    for (int f_ = 0; f_ < 2; ++f_) {
      int rowf = ((f_ << 1) + (i15 >> 3)) * 1024 + u0 + s_ * 8 + (i15 & 7);
      bias0[s_][f_] = (kway == 0) ? b0[rowf] : 0.f;
      bias1[s_][f_] = (kway == 0) ? b1[rowf] : 0.f;
    }

  // staging maps: 1024 bf16x8 slots (32 rows x 32), 4 per thread
  int grow[4], ldsoff[4];
#pragma unroll
  for (int cc = 0; cc < 4; ++cc) {
    int slot = cc * 256 + tid;
    int row = slot >> 5, c = slot & 31;
    grow[cc]   = ((m0 + row) << 10) + (c << 3);
    ldsoff[cc] = (row << 8) + ((c ^ (row & 7)) << 3);
  }

  bf16x8 v[4];
  auto stage_ld = [&](const u16* src, int kbase) {   // nt: LLC-coherent reads
#pragma unroll
    for (int cc = 0; cc < 4; ++cc)
      v[cc] = __builtin_nontemporal_load((const bf16x8*)(src + grow[cc] + kbase));
  };
  auto stage_st = [&]() {
#pragma unroll
    for (int cc = 0; cc < 4; ++cc)
      *(bf16x8*)&Abuf[ldsoff[cc]] = v[cc];
  };

  auto stage_x = [&](int t) {   // x tile 32x64 f32 -> bf16 into Abuf
    int row = tid >> 3, c8 = tid & 7;
    const float* g = x + ((size_t)(m0 + row) * 512 + t) * 64 + (c8 << 3);
    float4 a0 = *(const float4*)g, a1 = *(const float4*)(g + 4);
    bf16x8 r;
    r[0] = (short)f2bf(a0.x); r[1] = (short)f2bf(a0.y);
    r[2] = (short)f2bf(a0.z); r[3] = (short)f2bf(a0.w);
    r[4] = (short)f2bf(a1.x); r[5] = (short)f2bf(a1.y);
    r[6] = (short)f2bf(a1.z); r[7] = (short)f2bf(a1.w);
    *(bf16x8*)&Abuf[(row << 8) + ((c8 ^ (row & 7)) << 3)] = r;
  };

  auto readA = [&](int mf, int kin) -> bf16x8 {
    int row = (mf << 4) | i15;
    int c = ((kin >> 3) + kq) ^ (row & 7);
    return *(const bf16x8*)&Abuf[(row << 8) + (c << 3)];
  };

  bf16x8 W0[2][2][2];      // [jj][s][f] single-bank L0 weights (32 regs)
  bf16x8 W1[2][2][2][2];   // [bank][jj][s][f] double-banked L1 weights (64)
  f32x4 acc0[2][2][2], acc1[2][2][2];   // [mf][s][f] (32+32 regs)

  auto acc_init = [&](f32x4 (&acc)[2][2][2], const float (&bias)[2][2]) {
#pragma unroll
    for (int mf = 0; mf < 2; ++mf)
#pragma unroll
      for (int s_ = 0; s_ < 2; ++s_)
#pragma unroll
        for (int f_ = 0; f_ < 2; ++f_) {
          float bv = bias[s_][f_];
          acc[mf][s_][f_][0] = bv; acc[mf][s_][f_][1] = bv;
          acc[mf][s_][f_][2] = bv; acc[mf][s_][f_][3] = bv;
        }
  };

  auto reduce2 = [&]() {   // 4 kway partials -> G[L][0] + G[L][1], both layers
    if (kway < 2) {
      const int ab = kway;
#pragma unroll
      for (int mf = 0; mf < 2; ++mf)
#pragma unroll
        for (int s_ = 0; s_ < 2; ++s_)
#pragma unroll
          for (int f_ = 0; f_ < 2; ++f_)
#pragma unroll
            for (int r = 0; r < 4; ++r) {
              int rr = (mf << 4) + (kq << 2) + r, cl = (s_ << 5) + (f_ << 4) + i15;
              G[0][ab][rr][cl] = acc0[mf][s_][f_][r];
              G[1][ab][rr][cl] = acc1[mf][s_][f_][r];
            }
    }
    __syncthreads();
    if (kway >= 2) {
      const int ab = kway - 2;
#pragma unroll
      for (int mf = 0; mf < 2; ++mf)
#pragma unroll
        for (int s_ = 0; s_ < 2; ++s_)
#pragma unroll
          for (int f_ = 0; f_ < 2; ++f_)
#pragma unroll
            for (int r = 0; r < 4; ++r) {
              int rr = (mf << 4) + (kq << 2) + r, cl = (s_ << 5) + (f_ << 4) + i15;
              G[0][ab][rr][cl] += acc0[mf][s_][f_][r];
              G[1][ab][rr][cl] += acc1[mf][s_][f_][r];
            }
    }
    __syncthreads();
  };

  auto ew = [&](int L, u16* hdst, bool wf32) {
    int row = tid >> 3, un = (tid & 7) << 1;   // 32 rows x 8 thr x 2 units
    float hq[2];
#pragma unroll
    for (int q = 0; q < 2; ++q) {
      int u = un + q;
      int cb = ((u >> 3) << 5) | (u & 7);
      float gi = G[L][0][row][cb]      + G[L][1][row][cb];
      float gf = G[L][0][row][cb + 8]  + G[L][1][row][cb + 8];
      float gg = G[L][0][row][cb + 16] + G[L][1][row][cb + 16];
      float go = G[L][0][row][cb + 24] + G[L][1][row][cb + 24];
      float ii = sigm(gi), ff = sigm(gf), g2 = tanh_(gg), oo = sigm(go);
      float c = ff * cbuf[L][row][u] + ii * g2;
      cbuf[L][row][u] = c;
      hq[q] = oo * tanh_(c);
    }
    size_t idx = ((size_t)(m0 + row) << 10) + u0 + un;
    st_u32_sc01((u32*)(hdst + idx), (u32)f2bf(hq[0]) | ((u32)f2bf(hq[1]) << 16));
    if (wf32) {
      st_f32_sc01(h1f + idx, hq[0]); st_f32_sc01(h1f + idx + 1, hq[1]);
    }
  };

  auto gridbar = [&](int t) {       // verbatim R7 leader-tree barrier
    __syncthreads();                // drains vmcnt -> sc01 h stores at LLC
    if (tid == 0) {
      const int g = blk & 7;
      u32* gc   = bar + g * 32;
      u32* root = bar + 256;
      u32* gen  = bar + 288 + g * 32;
      const u32 p1 = (u32)(t + 1);
      __hip_atomic_fetch_add(gc, 1u, __ATOMIC_RELAXED, __HIP_MEMORY_SCOPE_AGENT);
      if (blk < 8) {
        while (ld_u32_sc01(gc) < 64u * p1) __builtin_amdgcn_s_sleep(4);
        __hip_atomic_fetch_add(root, 1u, __ATOMIC_RELAXED, __HIP_MEMORY_SCOPE_AGENT);
        while (ld_u32_sc01(root) < 8u * p1) __builtin_amdgcn_s_sleep(2);
        st_u32_sc01(gen, p1);
      } else {
        while (ld_u32_sc01(gen) < p1) __builtin_amdgcn_s_sleep(4);
      }
    }
    __syncthreads();
  };

  // ---------------- phase loop: phase t = { L0(t), L1(t-1) } fused ----------
#pragma unroll 1
  for (int t = 0; t <= 512; ++t) {
    const u16* h0rd = h0b + ((t + 1) & 1) * HB;   // h0(t-1)
    u16* h0wr = h0b + (t & 1) * HB;               // h0(t)
    const u16* h1rd = h1b + (t & 1) * HB;         // h1(t-2)
    u16* h1wr = h1b + ((t + 1) & 1) * HB;         // h1(t-1)
    const bool dL0 = (t < 512), dL1 = (t >= 1);

    if (dL0) acc_init(acc0, bias0);
    if (dL1) acc_init(acc1, bias1);

    // prologue: x tile + first h0 chunk + first weights in flight
    if (dL0) stage_x(t);
    stage_ld(h0rd, 0);
    if (dL1) LDW1(0, 0);
    if (dL0) LDW0(0);
    __syncthreads();                   // x tile published
    if (dL0 && kway < 2) {             // x-tick (ksteps 0,1 of K=64)
      u32 ox0 = bX[0], ox1 = bX[1];
      asm volatile("" : "+v"(ox0), "+v"(ox1));
      bf16x8 X00 = *(const bf16x8*)(X0p + ox0);
      bf16x8 X01 = *(const bf16x8*)(X0p + ox0 + 512u);
      bf16x8 X10 = *(const bf16x8*)(X0p + ox1);
      bf16x8 X11 = *(const bf16x8*)(X0p + ox1 + 512u);
      const int kin = kway << 5;
#pragma unroll
      for (int mf = 0; mf < 2; ++mf) {
        bf16x8 a = readA(mf, kin);
        acc0[mf][0][0] = MFMA(a, X00, acc0[mf][0][0], 0, 0, 0);
        acc0[mf][0][1] = MFMA(a, X01, acc0[mf][0][1], 0, 0, 0);
        acc0[mf][1][0] = MFMA(a, X10, acc0[mf][1][0], 0, 0, 0);
        acc0[mf][1][1] = MFMA(a, X11, acc0[mf][1][1], 0, 0, 0);
      }
    }
    __syncthreads();                   // x consumed
    stage_st(); __syncthreads();       // Abuf <- h0 chunk0

    // windows c=0..3: h0 chunk c feeds L0 (W0[c]) and L1 (W1 chunk c = Wx1)
    stage_ld(h0rd, 256);
    if (dL1) LDW1(1, 1);
    if (dL0) { CHUNK0(); LDW0(1); }
    if (dL1) CHUNK1(0);
    __syncthreads(); stage_st(); __syncthreads();

    stage_ld(h0rd, 512);
    if (dL1) LDW1(0, 2);
    if (dL0) { CHUNK0(); LDW0(2); }
    if (dL1) CHUNK1(1);
    __syncthreads(); stage_st(); __syncthreads();

    stage_ld(h0rd, 768);
    if (dL1) LDW1(1, 3);
    if (dL0) { CHUNK0(); LDW0(3); }
    if (dL1) CHUNK1(0);
    __syncthreads(); stage_st(); __syncthreads();

    if (dL1) { stage_ld(h1rd, 0); LDW1(0, 4); }
    if (dL0) CHUNK0();
    if (dL1) CHUNK1(1);
    __syncthreads();
    if (dL1) stage_st();
    __syncthreads();

    // windows c=4..7: h1 chunks feed L1 (W1 chunks 4..7 = Wh1)
    if (dL1) {
      stage_ld(h1rd, 256); LDW1(1, 5); CHUNK1(0);
      __syncthreads(); stage_st(); __syncthreads();
      stage_ld(h1rd, 512); LDW1(0, 6); CHUNK1(1);
      __syncthreads(); stage_st(); __syncthreads();
      stage_ld(h1rd, 768); LDW1(1, 7); CHUNK1(0);
      __syncthreads(); stage_st(); __syncthreads();
      CHUNK1(1);
    }

    reduce2();
    if (dL0) ew(0, h0wr, false);
    if (dL1) ew(1, h1wr, t == 512);

    gridbar(t);
  }

  // ---------------- fc epilogue (verbatim R7) ----------------
  if (blk < 64) {
    const int row = (blk << 2) | w;
    const float* hrow = h1f + ((size_t)row << 10);
#pragma unroll 1
    for (int o = 0; o < 12; ++o) {
      const float* wrow = fcW + o * 1024;
      float p = 0.f;
#pragma unroll
      for (int j = 0; j < 16; ++j) {
        int k = (j << 6) | lane;
        p += __builtin_nontemporal_load(hrow + k) * wrow[k];
      }
#pragma unroll
      for (int off = 32; off > 0; off >>= 1) p += __shfl_down(p, off, 64);
      if (lane == 0) out[row * 12 + o] = p + fcb[o];
    }
  }
}

extern "C" void kernel_launch(void* const* d_in, const int* in_sizes, int n_in,
                              void* d_out, int out_size, void* d_ws, size_t ws_size,
                              hipStream_t stream) {
  (void)in_sizes; (void)n_in; (void)out_size; (void)ws_size;
  const float* x   = (const float*)d_in[0];
  const float* Wx0 = (const float*)d_in[1];
  const float* Wh0 = (const float*)d_in[2];
  const float* b0  = (const float*)d_in[3];
  const float* Wx1 = (const float*)d_in[4];
  const float* Wh1 = (const float*)d_in[5];
  const float* b1  = (const float*)d_in[6];
  const float* fcW = (const float*)d_in[7];
  const float* fcb = (const float*)d_in[8];

  char* ws = (char*)d_ws;
  u16* W1p   = (u16*)ws;                          // 16 MiB packed Wx1|Wh1
  u16* W0p   = (u16*)(ws + (16u << 20));          //  8 MiB packed Wh0
  u16* X0p   = (u16*)(ws + (24u << 20));          // 512 KiB packed Wx0
  u16* h0b   = (u16*)(ws + (25u << 20));          // 2 x 512 KiB
  u16* h1b   = (u16*)(ws + (26u << 20));          // 2 x 512 KiB
  float* h1f = (float*)(ws + (27u << 20));        // 1 MiB
  u32* bar   = (u32*)(ws + (28u << 20));          // counters

  hipMemsetAsync(ws + (25u << 20) + (1 << 19), 0, 1 << 19, stream);  // h0b[1]
  hipMemsetAsync(ws + (26u << 20) + (1 << 19), 0, 1 << 19, stream);  // h1b[1]
  hipMemsetAsync(bar, 0, 4096, stream);

  wconv<<<6272, 256, 0, stream>>>(Wx0, Wh0, Wx1, Wh1, W1p, W0p, X0p);
  lstm_persist<<<512, 256, 0, stream>>>(x, b0, b1, fcW, fcb,
                                        W1p, W0p, X0p,
                                        h0b, h1b, h1f, bar, (float*)d_out);
}

// Round 13
// 8563.744 us; speedup vs baseline: 1.6397x; 1.3044x over previous
//
#include <hip/hip_runtime.h>

// ============================================================================
// 2-layer LSTM, persistent kernel, MI355X — round 13.
// R7/R12 regression analysis: phase time tracks BARRIER-WINDOW COUNT, not
// traffic (R7 19 windows/16.5us, R12 27 windows/21.8us, both ~0.8us/window).
// Cause: __syncthreads = s_waitcnt vmcnt(0) lgkmcnt(0) + s_barrier -> every
// window drains its own just-issued LLC prefetch loads (~700cy, twice).
// R13 = R7 + ONE mechanism (T3/T4 counted-wait barriers): intra-phase
// barriers become BARL = s_waitcnt lgkmcnt(0); s_barrier (LDS-publish only,
// vmcnt stays in flight across barriers). W-loads drain a full window later
// (hidden); stage-loads drain at stage_st's compiler vmcnt with CHUNK time
// already elapsed. reduce2/gridbar keep full __syncthreads (gridbar's drains
// sc01 h stores -> coherence unchanged).
// Everything else byte-identical to R7 (8.45 ms, absmax 4.9e-3, proven).
// ============================================================================

typedef unsigned int u32;
typedef unsigned short u16;
typedef __attribute__((ext_vector_type(8))) short bf16x8;
typedef __attribute__((ext_vector_type(4))) float f32x4;

#define MFMA __builtin_amdgcn_mfma_f32_16x16x32_bf16
#define HB (256 * 1024)   // h buffer elems per parity

// LDS-publish barrier: ds ops complete, global loads STAY IN FLIGHT.
#define BARL() do {                                                            \
  asm volatile("s_waitcnt lgkmcnt(0)" ::: "memory");                           \
  __builtin_amdgcn_s_barrier();                                                \
  asm volatile("" ::: "memory");                                               \
} while (0)

__device__ __forceinline__ u16 f2bf(float f) {
  u32 u = __float_as_uint(f);
  u += 0x7fffu + ((u >> 16) & 1u);   // RNE (inputs finite)
  return (u16)(u >> 16);
}
__device__ __forceinline__ float sigm(float v) { return 1.f / (1.f + __expf(-v)); }
__device__ __forceinline__ float tanh_(float v) { return 1.f - 2.f / (__expf(2.f * v) + 1.f); }

__device__ __forceinline__ u32 ld_u32_sc01(const u32* p) {
  u32 v;
  asm volatile("global_load_dword %0, %1, off sc0 sc1\n\ts_waitcnt vmcnt(0)"
               : "=v"(v) : "v"(p) : "memory");
  return v;
}
__device__ __forceinline__ void st_u32_sc01(u32* p, u32 v) {
  asm volatile("global_store_dword %0, %1, off sc0 sc1" :: "v"(p), "v"(v) : "memory");
}
__device__ __forceinline__ void st_f32_sc01(float* p, float v) {
  asm volatile("global_store_dword %0, %1, off sc0 sc1" :: "v"(p), "v"(v) : "memory");
}

// ---------------- prologue: f32 -> bf16 packed-fragment weights ----------------
// (verbatim from R7)
__global__ void __launch_bounds__(256) wconv(
    const float* __restrict__ Wx0, const float* __restrict__ Wh0,
    const float* __restrict__ Wx1, const float* __restrict__ Wh1,
    u16* __restrict__ W1p, u16* __restrict__ W0p, u16* __restrict__ X0p) {
  const u32 NG1 = 1048576u, NG0 = 524288u, NGX = 32768u;
  u32 g = blockIdx.x * 256u + threadIdx.x;
  const float* src; u16* dst;
  if (g < NG1) {
    u32 lane = g & 63u, f = (g >> 6) & 1u, jj = (g >> 7) & 1u, c = (g >> 8) & 7u;
    u32 kway = (g >> 11) & 3u, s = (g >> 13) & 1u, u0idx = g >> 14;
    u32 i15 = lane & 15u, kq = lane >> 4;
    u32 row = (2u * f + (i15 >> 3)) * 1024u + u0idx * 16u + s * 8u + (i15 & 7u);
    u32 k = (kway + 4u * (2u * c + jj)) * 32u + kq * 8u;
    src = (k < 1024u) ? Wx1 + (size_t)row * 1024 + k
                      : Wh1 + (size_t)row * 1024 + (k - 1024u);
    dst = W1p + (size_t)g * 8;
  } else if (g < NG1 + NG0) {
    u32 h = g - NG1;
    u32 lane = h & 63u, f = (h >> 6) & 1u, jj = (h >> 7) & 1u, c = (h >> 8) & 3u;
    u32 kway = (h >> 10) & 3u, s = (h >> 12) & 1u, u0idx = h >> 13;
    u32 i15 = lane & 15u, kq = lane >> 4;
    u32 row = (2u * f + (i15 >> 3)) * 1024u + u0idx * 16u + s * 8u + (i15 & 7u);
    u32 k = (kway + 4u * (2u * c + jj)) * 32u + kq * 8u;
    src = Wh0 + (size_t)row * 1024 + k;
    dst = W0p + (size_t)h * 8;
  } else if (g < NG1 + NG0 + NGX) {
    u32 h = g - NG1 - NG0;
    u32 lane = h & 63u, f = (h >> 6) & 1u, kway = (h >> 7) & 1u;
    u32 s = (h >> 8) & 1u, u0idx = h >> 9;
    u32 i15 = lane & 15u, kq = lane >> 4;
    u32 row = (2u * f + (i15 >> 3)) * 1024u + u0idx * 16u + s * 8u + (i15 & 7u);
    u32 k = kway * 32u + kq * 8u;
    src = Wx0 + (size_t)row * 64 + k;
    dst = X0p + (size_t)h * 8;
  } else return;
  float4 v0 = *(const float4*)src, v1 = *(const float4*)(src + 4);
  bf16x8 r;
  r[0] = (short)f2bf(v0.x); r[1] = (short)f2bf(v0.y);
  r[2] = (short)f2bf(v0.z); r[3] = (short)f2bf(v0.w);
  r[4] = (short)f2bf(v1.x); r[5] = (short)f2bf(v1.y);
  r[6] = (short)f2bf(v1.z); r[7] = (short)f2bf(v1.w);
  *(bf16x8*)dst = r;
}

// ---- per-chunk weight load: bank literal, per-call opaque offset ----
#define LDW(bank, c) do {                                                      \
  u32 o0_ = bW[0] + (u32)((c) * 2048), o1_ = bW[1] + (u32)((c) * 2048);        \
  asm volatile("" : "+v"(o0_), "+v"(o1_));                                     \
  _Pragma("unroll")                                                            \
  for (int jj_ = 0; jj_ < 2; ++jj_)                                            \
    _Pragma("unroll")                                                          \
    for (int f_ = 0; f_ < 2; ++f_) {                                           \
      W[bank][jj_][0][f_] = *(const bf16x8*)(WP + o0_ + (u32)(jj_*1024+f_*512));\
      W[bank][jj_][1][f_] = *(const bf16x8*)(WP + o1_ + (u32)(jj_*1024+f_*512));\
    }                                                                          \
} while (0)

// ---- per-chunk MFMA: 2 ksteps x 4 m-frags x 4 (s,f) n-frags = 32 MFMA ----
#define CHUNK(bank) do {                                                       \
  _Pragma("unroll")                                                            \
  for (int jj_ = 0; jj_ < 2; ++jj_) {                                          \
    const int kin_ = (kway + (jj_ << 2)) << 5;                                 \
    _Pragma("unroll")                                                          \
    for (int mf_ = 0; mf_ < 4; ++mf_) {                                        \
      bf16x8 a_ = readA(mf_, kin_);                                            \
      _Pragma("unroll")                                                        \
      for (int s_ = 0; s_ < 2; ++s_)                                           \
        _Pragma("unroll")                                                      \
        for (int f_ = 0; f_ < 2; ++f_)                                         \
          acc[mf_][s_][f_] = MFMA(a_, W[bank][jj_][s_][f_],                    \
                                  acc[mf_][s_][f_], 0, 0, 0);                  \
    }                                                                          \
  }                                                                            \
} while (0)

__global__ void __launch_bounds__(256, 2)
lstm_persist(const float* __restrict__ x,
             const float* __restrict__ b0, const float* __restrict__ b1,
             const float* __restrict__ fcW, const float* __restrict__ fcb,
             const u16* __restrict__ W1p, const u16* __restrict__ W0p,
             const u16* __restrict__ X0p,
             u16* __restrict__ h0b, u16* __restrict__ h1b,
             float* __restrict__ h1f, u32* __restrict__ bar,
             float* __restrict__ out)
{
  const int tid = threadIdx.x, blk = blockIdx.x;
  const int lane = tid & 63, w = tid >> 6;
  const int kway = w;                 // wave = k-split lane (0..3)
  const int L = blk >> 8;             // 0: layer0 WG, 1: layer1 WG
  const int sub = blk & 255;
  const int m0 = (sub >> 6) << 6;     // batch tile base
  const int u0idx = sub & 63;
  const int u0 = u0idx << 4;          // hidden-unit base

  __shared__ short Abuf[64 * 256];    // single 32KB A chunk
  __shared__ float gA[64][68];        // k-reduce region A
  __shared__ float gB[64][68];        // k-reduce region B
  __shared__ float cbuf[64][16];      // persistent c state (own layer)

  for (int i = tid; i < 64 * 16; i += 256) ((float*)cbuf)[i] = 0.f;

  const int i15 = lane & 15, kq = lane >> 4;

  // packed-weight base offsets for both s-halves (u32 elem offsets)
  u32 bW[2], bX[2];
#pragma unroll
  for (int s_ = 0; s_ < 2; ++s_) {
    u32 key = (u32)((u0idx << 1) | s_);
    bW[s_] = ((key << 2) | (u32)kway) * (L ? 16384u : 8192u) + (u32)lane * 8u;
    bX[s_] = ((key << 1) | (u32)kway) * 1024u + (u32)lane * 8u;  // kway<2 only
  }
  const u16* WP = L ? W1p : W0p;

  float bias[2][2];
#pragma unroll
  for (int s_ = 0; s_ < 2; ++s_)
#pragma unroll
    for (int f_ = 0; f_ < 2; ++f_) {
      int rowf = ((f_ << 1) + (i15 >> 3)) * 1024 + u0 + s_ * 8 + (i15 & 7);
      bias[s_][f_] = (kway == 0) ? (L ? b1[rowf] : b0[rowf]) : 0.f;
    }

  // staging maps: 2048 bf16x8 slots (64 rows x 32), 8 per thread
  int grow[8], ldsoff[8];
#pragma unroll
  for (int cc = 0; cc < 8; ++cc) {
    int slot = cc * 256 + tid;
    int row = slot >> 5, c = slot & 31;
    grow[cc]   = ((m0 + row) << 10) + (c << 3);
    ldsoff[cc] = (row << 8) + ((c ^ (row & 7)) << 3);
  }

  bf16x8 v[8];
  auto stage_ld = [&](const u16* src, int kbase) {   // nt: LLC-coherent reads
#pragma unroll
    for (int cc = 0; cc < 8; ++cc)
      v[cc] = __builtin_nontemporal_load((const bf16x8*)(src + grow[cc] + kbase));
  };
  auto stage_st = [&]() {
#pragma unroll
    for (int cc = 0; cc < 8; ++cc)
      *(bf16x8*)&Abuf[ldsoff[cc]] = v[cc];
  };

  auto stage_x = [&](int t) {   // x tile 64x64 f32 -> bf16 into Abuf
    int row = tid >> 2, c4 = tid & 3;
    const float* g = x + ((size_t)(m0 + row) * 512 + t) * 64 + (c4 << 4);
    float4 a0 = *(const float4*)g,       a1 = *(const float4*)(g + 4);
    float4 a2 = *(const float4*)(g + 8), a3 = *(const float4*)(g + 12);
    bf16x8 r0, r1;
    r0[0] = (short)f2bf(a0.x); r0[1] = (short)f2bf(a0.y);
    r0[2] = (short)f2bf(a0.z); r0[3] = (short)f2bf(a0.w);
    r0[4] = (short)f2bf(a1.x); r0[5] = (short)f2bf(a1.y);
    r0[6] = (short)f2bf(a1.z); r0[7] = (short)f2bf(a1.w);
    r1[0] = (short)f2bf(a2.x); r1[1] = (short)f2bf(a2.y);
    r1[2] = (short)f2bf(a2.z); r1[3] = (short)f2bf(a2.w);
    r1[4] = (short)f2bf(a3.x); r1[5] = (short)f2bf(a3.y);
    r1[6] = (short)f2bf(a3.z); r1[7] = (short)f2bf(a3.w);
    int c = c4 << 1;
    *(bf16x8*)&Abuf[(row << 8) + (((c    ) ^ (row & 7)) << 3)] = r0;
    *(bf16x8*)&Abuf[(row << 8) + (((c + 1) ^ (row & 7)) << 3)] = r1;
  };

  auto readA = [&](int mf, int kin) -> bf16x8 {
    int row = (mf << 4) | i15;
    int c = ((kin >> 3) + kq) ^ (row & 7);
    return *(const bf16x8*)&Abuf[(row << 8) + (c << 3)];
  };

  bf16x8 W[2][2][2][2];   // [bank][jj][s][f] double-banked weights (64 regs)
  f32x4 acc[4][2][2];     // [mf][s][f] (64 regs)

  auto acc_init = [&]() {
#pragma unroll
    for (int mf = 0; mf < 4; ++mf)
#pragma unroll
      for (int s_ = 0; s_ < 2; ++s_)
#pragma unroll
        for (int f_ = 0; f_ < 2; ++f_) {
          float bv = bias[s_][f_];
          acc[mf][s_][f_][0] = bv; acc[mf][s_][f_][1] = bv;
          acc[mf][s_][f_][2] = bv; acc[mf][s_][f_][3] = bv;
        }
  };

  auto reduce2 = [&]() {   // 4 kway partials -> gA + gB (full __syncthreads)
    if (kway < 2) {
      float (*g)[68] = kway ? gB : gA;
#pragma unroll
      for (int mf = 0; mf < 4; ++mf)
#pragma unroll
        for (int s_ = 0; s_ < 2; ++s_)
#pragma unroll
          for (int f_ = 0; f_ < 2; ++f_)
#pragma unroll
            for (int r = 0; r < 4; ++r)
              g[(mf << 4) + (kq << 2) + r][(s_ << 5) + (f_ << 4) + i15] = acc[mf][s_][f_][r];
    }
    __syncthreads();
    if (kway >= 2) {
      float (*g)[68] = (kway == 3) ? gB : gA;
#pragma unroll
      for (int mf = 0; mf < 4; ++mf)
#pragma unroll
        for (int s_ = 0; s_ < 2; ++s_)
#pragma unroll
          for (int f_ = 0; f_ < 2; ++f_)
#pragma unroll
            for (int r = 0; r < 4; ++r)
              g[(mf << 4) + (kq << 2) + r][(s_ << 5) + (f_ << 4) + i15] += acc[mf][s_][f_][r];
    }
    __syncthreads();
  };

  auto ew = [&](u16* hdst, bool wf32) {
    int row = tid >> 2, un = (tid & 3) << 2;   // 4 units per thread
    float hq[4];
#pragma unroll
    for (int q = 0; q < 4; ++q) {
      int u = un + q;
      int cb = ((u >> 3) << 5) | (u & 7);
      float gi = gA[row][cb]      + gB[row][cb];
      float gf = gA[row][cb + 8]  + gB[row][cb + 8];
      float gg = gA[row][cb + 16] + gB[row][cb + 16];
      float go = gA[row][cb + 24] + gB[row][cb + 24];
      float ii = sigm(gi), ff = sigm(gf), g2 = tanh_(gg), oo = sigm(go);
      float c = ff * cbuf[row][u] + ii * g2;
      cbuf[row][u] = c;
      hq[q] = oo * tanh_(c);
    }
    size_t idx = ((size_t)(m0 + row) << 10) + u0 + un;
    st_u32_sc01((u32*)(hdst + idx),     (u32)f2bf(hq[0]) | ((u32)f2bf(hq[1]) << 16));
    st_u32_sc01((u32*)(hdst + idx + 2), (u32)f2bf(hq[2]) | ((u32)f2bf(hq[3]) << 16));
    if (wf32) {
      st_f32_sc01(h1f + idx,     hq[0]); st_f32_sc01(h1f + idx + 1, hq[1]);
      st_f32_sc01(h1f + idx + 2, hq[2]); st_f32_sc01(h1f + idx + 3, hq[3]);
    }
  };

  auto gridbar = [&](int t) {       // verbatim R7 leader-tree barrier
    __syncthreads();                // FULL drain: sc01 h stores reach LLC
    if (tid == 0) {
      const int g = blk & 7;
      u32* gc   = bar + g * 32;
      u32* root = bar + 256;
      u32* gen  = bar + 288 + g * 32;
      const u32 p1 = (u32)(t + 1);
      __hip_atomic_fetch_add(gc, 1u, __ATOMIC_RELAXED, __HIP_MEMORY_SCOPE_AGENT);
      if (blk < 8) {
        while (ld_u32_sc01(gc) < 64u * p1) __builtin_amdgcn_s_sleep(4);
        __hip_atomic_fetch_add(root, 1u, __ATOMIC_RELAXED, __HIP_MEMORY_SCOPE_AGENT);
        while (ld_u32_sc01(root) < 8u * p1) __builtin_amdgcn_s_sleep(2);
        st_u32_sc01(gen, p1);
      } else {
        while (ld_u32_sc01(gen) < p1) __builtin_amdgcn_s_sleep(4);
      }
    }
    __syncthreads();
  };

  if (L == 0) {
    // ---------------- layer-0 WGs: compute h0(t) each phase ----------------
#pragma unroll 1
    for (int t = 0; t <= 512; ++t) {
      if (t < 512) {
        const u16* h0rd = h0b + ((t + 1) & 1) * HB;
        u16* h0wr = h0b + (t & 1) * HB;
        acc_init();
        stage_x(t);                        // Abuf <- x tile (ds writes)
        stage_ld(h0rd, 0);                 // prefetch h0 chunk0 (stays in flight)
        bf16x8 X[2][2];
        if (kway < 2) {
          u32 ox0 = bX[0], ox1 = bX[1];
          asm volatile("" : "+v"(ox0), "+v"(ox1));
          X[0][0] = *(const bf16x8*)(X0p + ox0);
          X[0][1] = *(const bf16x8*)(X0p + ox0 + 512u);
          X[1][0] = *(const bf16x8*)(X0p + ox1);
          X[1][1] = *(const bf16x8*)(X0p + ox1 + 512u);
        }
        LDW(0, 0);                         // W chunk0 -> bank0
        BARL();                            // x tile published (vm in flight)
        if (kway < 2) {                    // x-tick (ksteps 0,1 of K=64)
          const int kin = kway << 5;
#pragma unroll
          for (int mf = 0; mf < 4; ++mf) {
            bf16x8 a = readA(mf, kin);
#pragma unroll
            for (int s_ = 0; s_ < 2; ++s_)
#pragma unroll
              for (int f_ = 0; f_ < 2; ++f_)
                acc[mf][s_][f_] = MFMA(a, X[s_][f_], acc[mf][s_][f_], 0, 0, 0);
          }
        }
        BARL();                            // x consumed
        stage_st(); BARL();                // Abuf <- h0 chunk0
        stage_ld(h0rd, 256); LDW(1, 1); CHUNK(0); BARL();
        stage_st(); BARL();
        stage_ld(h0rd, 512); LDW(0, 2); CHUNK(1); BARL();
        stage_st(); BARL();
        stage_ld(h0rd, 768); LDW(1, 3); CHUNK(0); BARL();
        stage_st(); BARL();
        CHUNK(1);
        reduce2();
        ew(h0wr, false);
      }
      gridbar(t);
    }
  } else {
    // -------------- layer-1 WGs: compute h1(t-1) each phase --------------
#pragma unroll 1
    for (int t = 0; t <= 512; ++t) {
      if (t >= 1) {
        const u16* h0rd = h0b + ((t + 1) & 1) * HB;   // h0(t-1)
        const u16* h1rd = h1b + (t & 1) * HB;         // h1(t-2)
        u16* h1wr = h1b + ((t + 1) & 1) * HB;         // h1(t-1)
        acc_init();
        stage_ld(h0rd, 0); LDW(0, 0);
        stage_st(); BARL();
        stage_ld(h0rd, 256); LDW(1, 1); CHUNK(0); BARL();
        stage_st(); BARL();
        stage_ld(h0rd, 512); LDW(0, 2); CHUNK(1); BARL();
        stage_st(); BARL();
        stage_ld(h0rd, 768); LDW(1, 3); CHUNK(0); BARL();
        stage_st(); BARL();
        stage_ld(h1rd, 0);   LDW(0, 4); CHUNK(1); BARL();
        stage_st(); BARL();
        stage_ld(h1rd, 256); LDW(1, 5); CHUNK(0); BARL();
        stage_st(); BARL();
        stage_ld(h1rd, 512); LDW(0, 6); CHUNK(1); BARL();
        stage_st(); BARL();
        stage_ld(h1rd, 768); LDW(1, 7); CHUNK(0); BARL();
        stage_st(); BARL();
        CHUNK(1);
        reduce2();
        ew(h1wr, t == 512);
      }
      gridbar(t);
    }
  }

  // ---------------- fc epilogue: out = h1(511) @ fcW.T + fcb ----------------
  if (blk < 64) {
    const int row = (blk << 2) | w;
    const float* hrow = h1f + ((size_t)row << 10);
#pragma unroll 1
    for (int o = 0; o < 12; ++o) {
      const float* wrow = fcW + o * 1024;
      float p = 0.f;
#pragma unroll
      for (int j = 0; j < 16; ++j) {
        int k = (j << 6) | lane;
        p += __builtin_nontemporal_load(hrow + k) * wrow[k];
      }
#pragma unroll
      for (int off = 32; off > 0; off >>= 1) p += __shfl_down(p, off, 64);
      if (lane == 0) out[row * 12 + o] = p + fcb[o];
    }
  }
}

extern "C" void kernel_launch(void* const* d_in, const int* in_sizes, int n_in,
                              void* d_out, int out_size, void* d_ws, size_t ws_size,
                              hipStream_t stream) {
  (void)in_sizes; (void)n_in; (void)out_size; (void)ws_size;
  const float* x   = (const float*)d_in[0];
  const float* Wx0 = (const float*)d_in[1];
  const float* Wh0 = (const float*)d_in[2];
  const float* b0  = (const float*)d_in[3];
  const float* Wx1 = (const float*)d_in[4];
  const float* Wh1 = (const float*)d_in[5];
  const float* b1  = (const float*)d_in[6];
  const float* fcW = (const float*)d_in[7];
  const float* fcb = (const float*)d_in[8];

  char* ws = (char*)d_ws;
  u16* W1p   = (u16*)ws;                          // 16 MiB packed Wx1|Wh1
  u16* W0p   = (u16*)(ws + (16u << 20));          //  8 MiB packed Wh0
  u16* X0p   = (u16*)(ws + (24u << 20));          // 512 KiB packed Wx0
  u16* h0b   = (u16*)(ws + (25u << 20));          // 2 x 512 KiB
  u16* h1b   = (u16*)(ws + (26u << 20));          // 2 x 512 KiB
  float* h1f = (float*)(ws + (27u << 20));        // 1 MiB
  u32* bar   = (u32*)(ws + (28u << 20));          // counters

  hipMemsetAsync(ws + (25u << 20) + (1 << 19), 0, 1 << 19, stream);  // h0b[1]
  hipMemsetAsync(ws + (26u << 20) + (1 << 19), 0, 1 << 19, stream);  // h1b[1]
  hipMemsetAsync(bar, 0, 4096, stream);

  wconv<<<6272, 256, 0, stream>>>(Wx0, Wh0, Wx1, Wh1, W1p, W0p, X0p);
  lstm_persist<<<512, 256, 0, stream>>>(x, b0, b1, fcW, fcb,
                                        W1p, W0p, X0p,
                                        h0b, h1b, h1f, bar, (float*)d_out);
}